// Round 5
// baseline (2373.468 us; speedup 1.0000x reference)
//
#include <hip/hip_runtime.h>
#include <cstddef>

// ---------------------------------------------------------------------------
// SNN forward, feed-forward pipeline. CORRECTNESS CONTRACT: reproduce R3's
// sequential-in-ascending-j fp32 fmaf chain per (t,b,o) (passed, 1.5e-5).
// R10 FACT: fmaf(+0, w, acc) == acc EXACTLY (acc never -0), so skipping
// zero-spike j's is bit-identical.
//
// Ladder: R13=814us L1 (champion structure: lane=o, reg=t, gate on SALU,
// 2 waves/SIMD). R14: gate as replicated VALU cndmask -> +50% VALU, worse.
// R15: t-split waves -> 2x W traffic, worse. R17: 1 wave/b @ 1 wave/SIMD ->
// latency-exposed (VALU 49.5%), worse. Triangulation: the per-act-j gate
// (select av per t) is the overhead above the 380us fmac floor.
// R18: T IN THE LANE. lane=(og 0..3, t16 0..15); regs=(tr 0..1, 16 o's).
//   - acc = 32 VGPR -> ~70-90 total regs -> 4-6 waves/SIMD (TLP hides L2).
//   - gate PER-LANE: 1 shift+and+mul seq (~6 VALU) serves all 32 fmacs of
//     the wave (12% overhead). NOT replicated like R14's per-t cndmask.
//   - sparsity: ballot(mw!=0) per 64-j window + s_ff1 iteration; ZERO cost
//     for inactive j (no per-j branch, no unconditional loads).
//   - W loads: 4x dwordx4 per (wave,act-j), half-wave broadcast addrs;
//     bytes per (b,act-j) conserved at 2KB.
//   - epilogue: per-wave LDS transpose [64][34] (1 barrier), then verbatim
//     LIF/LI chain per lane (o = lane).
// Order: ascending j (ctz LSB->MSB within window, windows ascending) ->
// identical chain to R3/R13.
// ---------------------------------------------------------------------------

#define THREADS 256

// WT offsets (floats): WT1[2048][512], WT2[512][512], WT3[512][256],
// WT4[256][128] (w4 zero-padded 100->128 cols)
#define WOFF1 0
#define WOFF2 1048576
#define WOFF3 1310720
#define WOFF4 1441792
#define WTOT  1474560

__global__ __launch_bounds__(THREADS) void prep_kernel(
    const float* __restrict__ w1, const float* __restrict__ w2,
    const float* __restrict__ w3, const float* __restrict__ w4,
    float* __restrict__ wt)
{
  int idx = blockIdx.x * THREADS + threadIdx.x;
  if (idx >= WTOT) return;
  if (idx < WOFF2) {
    int j = idx >> 9, o = idx & 511;
    wt[idx] = w1[o * 2048 + j];
  } else if (idx < WOFF3) {
    int r = idx - WOFF2, j = r >> 9, o = r & 511;
    wt[idx] = w2[o * 512 + j];
  } else if (idx < WOFF4) {
    int r = idx - WOFF3, j = r >> 8, o = r & 255;
    wt[idx] = w3[o * 512 + j];
  } else {
    int r = idx - WOFF4, j = r >> 7, o = r & 127;
    wt[idx] = (o < 100) ? w4[o * 256 + j] : 0.0f;
  }
}

// Encoder (verbatim R3 arithmetic); writes em[b][j] word = bits over t.
__global__ __launch_bounds__(THREADS) void enc_kernel(
    const float* __restrict__ x, const float* __restrict__ fscale,
    unsigned* __restrict__ em, int b0)
{
  int idx = blockIdx.x * THREADS + threadIdx.x;
  int b = idx >> 11, j = idx & 2047;
  float c = 2.0f * fscale[0] * x[((size_t)(b0 + b) << 11) + j];
  float v = 0.0f;
  unsigned m = 0u;
#pragma unroll
  for (int t = 0; t < 32; ++t) {
    v = v + 0.1f * (c - v);
    unsigned z = ((v - 0.33f) > 0.0f) ? 1u : 0u;
    m |= z << t;
    if (z) v = 0.0f;
  }
  em[idx] = m;
}

// ---------------------------------------------------------------------------
// Sparse-j fused GEMM(+LIF / +LI readout), t-in-lane layout.
//   mIn: em-format masks [b][J], word = bits over t (wave-uniform per j)
//   WT:  [j][o] pre-transposed weights (rows L2-resident)
// Wave covers 64 o's x 32 t for one b. lane=(og=lane>>4, t16=lane&15);
// per-lane: o = obase + og*16 + k (k 0..15), t = t16 + 16*tr (tr 0..1);
// acc a0[16] (tr=0), a1[16] (tr=1). Active j's via ballot+ctz (scalar pipe,
// zero inactive cost). W row frag: 4x dwordx4 at wbase + j*O + og*16.
// ---------------------------------------------------------------------------
template <int O, bool FINAL>
__global__ __launch_bounds__(THREADS, 4) void gemm_sparse(
    const unsigned* __restrict__ mIn, const float* __restrict__ WT,
    int J, const float* __restrict__ es,
    unsigned* __restrict__ mOut, float* __restrict__ out, int bbase)
{
  typedef float fv4 __attribute__((ext_vector_type(4)));
  constexpr int WPB = O / 64;                // waves per b (8/4/2)
  const int tid = threadIdx.x;
  const int lane = tid & 63, wvid = tid >> 6;
  const int t16 = lane & 15;                 // t within half
  const int og  = lane >> 4;                 // o-group 0..3
  int b, obase;
  if constexpr (WPB >= 4) {
    constexpr int BLKS = WPB / 4;            // blocks per b (2 for O=512)
    b = blockIdx.x / BLKS;
    obase = (blockIdx.x % BLKS) * 256 + wvid * 64;
  } else {
    constexpr int BPB = 4 / WPB;             // b's per block (2 for O=128)
    b = blockIdx.x * BPB + wvid / WPB;
    obase = (wvid % WPB) * 64;
  }
  const float* const wbase = WT + obase;     // + j*O + og*16 at load time
  float scalef = es ? 5.0f * es[0] : 1.0f;   // same expr as R3
  const int scale_i =
      __builtin_amdgcn_readfirstlane(__float_as_int(scalef));

  __shared__ float xp[4][64][34];            // per-wave transpose slab

  float a0[16], a1[16];
#pragma unroll
  for (int k = 0; k < 16; ++k) { a0[k] = 0.0f; a1[k] = 0.0f; }

  const unsigned* mrow = mIn + (size_t)b * J;
  const int NW = J >> 6;                     // 64-j windows (32/8/8/4)

  unsigned mwA = mrow[lane];                 // window 0: word per lane
#pragma unroll 1
  for (int w = 0; w < NW; ++w) {
    // prefetch next window (last: benign same-row reload)
    unsigned mwB = mrow[((w + 1 < NW) ? (w + 1) : w) * 64 + lane];
    unsigned long long act = __ballot(mwA != 0u);  // SGPR-pair active set
    const float* const wwin = wbase + (size_t)(w << 6) * O;
    while (act) {
      int jj = __builtin_ctzll(act);         // s_ff1; ascending j order
      act &= act - 1;
      unsigned ws = (unsigned)__builtin_amdgcn_readlane((int)mwA, jj);
      const float* p = wwin + (size_t)jj * O + og * 16;
      fv4 f0 = *(const fv4*)(p);
      fv4 f1 = *(const fv4*)(p + 4);
      fv4 f2 = *(const fv4*)(p + 8);
      fv4 f3 = *(const fv4*)(p + 12);
      // per-lane gate: av_tr = bit(ws, t16+16*tr) ? scale : 0 (exact)
      unsigned sh = ws >> t16;
      float av0 = __int_as_float((int)(sh & 1u) * scale_i);
      float av1 = __int_as_float((int)((sh >> 16) & 1u) * scale_i);
#pragma unroll
      for (int c = 0; c < 4; ++c) {
        a0[c]      = fmaf(av0, f0[c], a0[c]);
        a1[c]      = fmaf(av1, f0[c], a1[c]);
        a0[4 + c]  = fmaf(av0, f1[c], a0[4 + c]);
        a1[4 + c]  = fmaf(av1, f1[c], a1[4 + c]);
        a0[8 + c]  = fmaf(av0, f2[c], a0[8 + c]);
        a1[8 + c]  = fmaf(av1, f2[c], a1[8 + c]);
        a0[12 + c] = fmaf(av0, f3[c], a0[12 + c]);
        a1[12 + c] = fmaf(av1, f3[c], a1[12 + c]);
      }
    }
    mwA = mwB;
  }

  // ---- epilogue: transpose acc (t-in-lane -> o-in-lane) via LDS, then
  //      verbatim R3 LIF/LI chain per lane's o. One barrier. ----
#pragma unroll
  for (int k = 0; k < 16; ++k) {
    xp[wvid][og * 16 + k][t16]      = a0[k];
    xp[wvid][og * 16 + k][t16 + 16] = a1[k];
  }
  __syncthreads();
  {
    float v = 0.0f, cur = 0.0f;
    unsigned zw = 0u;
#pragma unroll
    for (int t2 = 0; t2 < 32; ++t2) {
      float a = xp[wvid][lane][t2];
      v = v + 0.1f * (cur - v);              // verbatim R3 lif_int / out_li
      if (!FINAL) {
        unsigned z = ((v - 0.33f) > 0.0f) ? 1u : 0u;
        zw |= z << t2;
        if (z) v = 0.0f;
      }
      cur = 0.8f * cur + a;
    }
    if (FINAL) {
      int o = obase + lane;
      if (o < 100) out[(size_t)(bbase + b) * 100 + o] = v;
    } else {
      mOut[(size_t)b * O + obase + lane] = zw;  // em-format for next layer
    }
  }
}

extern "C" void kernel_launch(void* const* d_in, const int* in_sizes, int n_in,
                              void* d_out, int out_size, void* d_ws, size_t ws_size,
                              hipStream_t stream)
{
  const float* x  = (const float*)d_in[0];
  const float* w1 = (const float*)d_in[1];
  const float* w2 = (const float*)d_in[2];
  const float* w3 = (const float*)d_in[3];
  const float* w4 = (const float*)d_in[4];
  const float* fs = (const float*)d_in[5];
  const float* es = (const float*)d_in[6];
  float* out = (float*)d_out;
  (void)in_sizes; (void)n_in; (void)out_size;

  // ws: WT (5.9 MB) + em + s1m + s2m + s3m (all em-format words)
  int Bc = 2048;
  auto need = [](int bc) -> size_t {
    return ((size_t)WTOT + (size_t)bc * (2048 + 512 + 512 + 256)) * 4;
  };
  while (Bc > 64 && need(Bc) > ws_size) Bc >>= 1;

  float* WT = (float*)d_ws;
  unsigned* em  = (unsigned*)(WT + WTOT);
  unsigned* s1m = em  + (size_t)Bc * 2048;
  unsigned* s2m = s1m + (size_t)Bc * 512;
  unsigned* s3m = s2m + (size_t)Bc * 512;

  prep_kernel<<<(WTOT + THREADS - 1) / THREADS, THREADS, 0, stream>>>(
      w1, w2, w3, w4, WT);

  for (int b0 = 0; b0 < 2048; b0 += Bc) {
    enc_kernel<<<(Bc * 2048) / THREADS, THREADS, 0, stream>>>(x, fs, em, b0);
    // L1: J=2048 -> O=512, scale = 5*encoder_scalar (2 blocks per b)
    gemm_sparse<512, false><<<Bc * 2, THREADS, 0, stream>>>(
        em, WT + WOFF1, 2048, es, s1m, nullptr, 0);
    // L2: J=512 -> O=512
    gemm_sparse<512, false><<<Bc * 2, THREADS, 0, stream>>>(
        s1m, WT + WOFF2, 512, nullptr, s2m, nullptr, 0);
    // L3: J=512 -> O=256 (1 block per b)
    gemm_sparse<256, false><<<Bc, THREADS, 0, stream>>>(
        s2m, WT + WOFF3, 512, nullptr, s3m, nullptr, 0);
    // L4 (readout): J=256 -> O=128 (padded), LI epilogue -> out (2 b/block)
    gemm_sparse<128, true><<<Bc / 2, THREADS, 0, stream>>>(
        s3m, WT + WOFF4, 256, nullptr, nullptr, out, b0);
  }
}

// Round 6
// 1215.238 us; speedup vs baseline: 1.9531x; 1.9531x over previous
//
#include <hip/hip_runtime.h>
#include <cstddef>

// ---------------------------------------------------------------------------
// SNN forward, feed-forward pipeline. CORRECTNESS CONTRACT: reproduce R3's
// sequential-in-ascending-j fp32 fmaf chain per (t,b,o) (passed, 1.5e-5).
// R10 FACT: fmaf(+0, w, acc) == acc EXACTLY (acc never -0), so skipping
// zero-spike j's is bit-identical.
//
// Ladder: R13=814us L1 (champion: lane=o, reg=t, unconditional depth-1
// ping-pong W prefetch, wave-uniform scalar gate, 2 waves/SIMD).
// R14 (gate sank to replicated VALU cndmask): +50% VALU instr, worse.
// R15 (t-split waves): 2x W traffic, worse. R17 (1 wave/b, 1 wave/SIMD):
// latency-exposed, worse. R18 (reactive ballot/ctz loads): loads issue
// AFTER serial mask chain -> latency-exposed, much worse. FETCH_SIZE is KB:
// W/masks are L2/L3-resident (~37MB/dispatch); prefetch-ahead ILP is what
// hides the bursty L2-scale latency — never give it up.
// R13 residual = 366us non-VALU band: gate SALU (3 chained ops x 32t x
// act-j ~= 73% busy on the CU-shared scalar unit; both resident waves stall
// together) + zero-active-group bubbles.
// R19 = R13 byte-for-byte EXCEPT the gate: inline-asm s_bitcmp1_b32(imm t)
// + s_cselect_b32 — 2 SALU/t, SCC-local pairs (independent across t),
// forced scalar (cannot sink to VALU, the R14 failure). fmaf(av,w,acc) with
// av in {scale,0} unchanged -> bit-identical.
// Dead ends verified: t-bit sparsity (acc runtime-indexed by t -> scratch;
// LDS-acc costs more than it saves); v_pk_fma_f32 (157.3TF = plain fma
// full-rate already, no packed gain).
// ---------------------------------------------------------------------------

#define THREADS 256

// WT offsets (floats): WT1[2048][512], WT2[512][512], WT3[512][256],
// WT4[256][128] (w4 zero-padded 100->128 cols)
#define WOFF1 0
#define WOFF2 1048576
#define WOFF3 1310720
#define WOFF4 1441792
#define WTOT  1474560

__global__ __launch_bounds__(THREADS) void prep_kernel(
    const float* __restrict__ w1, const float* __restrict__ w2,
    const float* __restrict__ w3, const float* __restrict__ w4,
    float* __restrict__ wt)
{
  int idx = blockIdx.x * THREADS + threadIdx.x;
  if (idx >= WTOT) return;
  if (idx < WOFF2) {
    int j = idx >> 9, o = idx & 511;
    wt[idx] = w1[o * 2048 + j];
  } else if (idx < WOFF3) {
    int r = idx - WOFF2, j = r >> 9, o = r & 511;
    wt[idx] = w2[o * 512 + j];
  } else if (idx < WOFF4) {
    int r = idx - WOFF3, j = r >> 8, o = r & 255;
    wt[idx] = w3[o * 512 + j];
  } else {
    int r = idx - WOFF4, j = r >> 7, o = r & 127;
    wt[idx] = (o < 100) ? w4[o * 256 + j] : 0.0f;
  }
}

// Encoder (verbatim R3 arithmetic); writes em[b][j] word = bits over t.
__global__ __launch_bounds__(THREADS) void enc_kernel(
    const float* __restrict__ x, const float* __restrict__ fscale,
    unsigned* __restrict__ em, int b0)
{
  int idx = blockIdx.x * THREADS + threadIdx.x;
  int b = idx >> 11, j = idx & 2047;
  float c = 2.0f * fscale[0] * x[((size_t)(b0 + b) << 11) + j];
  float v = 0.0f;
  unsigned m = 0u;
#pragma unroll
  for (int t = 0; t < 32; ++t) {
    v = v + 0.1f * (c - v);
    unsigned z = ((v - 0.33f) > 0.0f) ? 1u : 0u;
    m |= z << t;
    if (z) v = 0.0f;
  }
  em[idx] = m;
}

// ---------------------------------------------------------------------------
// Sparse-j fused GEMM(+LIF / +LI readout), LDS-free, ping-pong pipelined.
//   mIn: em-format masks [b][J], word = bits over t (wave-uniform per j)
//   WT:  [j][o] pre-transposed weights (rows L2-resident)
// Block: 4 waves; wave = (b, o-slice); lane owns NAO consecutive o's,
// acc[32][NAO] holds all t. Groups of 4 j; W loads unconditional, depth-1;
// masks depth-2; FMA bodies conditional (the sparsity win).
// Gate: s_bitcmp1_b32(imm t) + s_cselect_b32 via inline asm (2 SALU/t).
// ---------------------------------------------------------------------------

// per-t gate + NAO fmacs; T must be a LITERAL 0..31 (stringified immediate)
#define GATE_T(T)                                                        \
  {                                                                      \
    int av_i;                                                            \
    asm("s_bitcmp1_b32 %1, " #T "\n\t"                                   \
        "s_cselect_b32 %0, %2, 0"                                        \
        : "=s"(av_i) : "s"(wj), "s"(scale_i) : "scc");                   \
    const float av = __int_as_float(av_i);                               \
    _Pragma("unroll")                                                    \
    for (int k = 0; k < NAO; ++k)                                        \
      acc[T][k] = fmaf(av, wv[jj][k], acc[T][k]);                        \
  }

template <int O, bool FINAL>
__global__ __launch_bounds__(THREADS, 2) void gemm_sparse(
    const unsigned* __restrict__ mIn, const float* __restrict__ WT,
    int J, const float* __restrict__ es,
    unsigned* __restrict__ mOut, float* __restrict__ out, int bbase)
{
  constexpr int NAO = (O >= 256) ? 4 : 2;    // o's per lane
  constexpr int WPB = O / (64 * NAO);        // waves per b
  constexpr int BPB = 4 / WPB;               // b's per block
  typedef float fv __attribute__((ext_vector_type(NAO)));
  const int tid = threadIdx.x;
  const int lane = tid & 63, wvid = tid >> 6;
  const int b = blockIdx.x * BPB + wvid / WPB;
  const int obase = (wvid % WPB) * (64 * NAO) + lane * NAO;
  const float* const wbase = WT + obase;     // row j at wbase + j*O
  float scalef = es ? 5.0f * es[0] : 1.0f;   // same expr as R3
  const int scale_i =
      __builtin_amdgcn_readfirstlane(__float_as_int(scalef));

  float acc[32][NAO];
#pragma unroll
  for (int t = 0; t < 32; ++t)
#pragma unroll
    for (int k = 0; k < NAO; ++k) acc[t][k] = 0.0f;

  const unsigned* mrow = mIn + (size_t)b * J;
  const int G = J >> 2;                      // groups of 4 j (G even)

  auto mload = [&](int g) -> uint4 {
    return *(const uint4*)(mrow + g * 4);    // wave-uniform address
  };
  auto rfl = [&](uint4 mq, unsigned* w) {
    w[0] = (unsigned)__builtin_amdgcn_readfirstlane((int)mq.x);
    w[1] = (unsigned)__builtin_amdgcn_readfirstlane((int)mq.y);
    w[2] = (unsigned)__builtin_amdgcn_readfirstlane((int)mq.z);
    w[3] = (unsigned)__builtin_amdgcn_readfirstlane((int)mq.w);
  };
  auto wloadU = [&](int g, fv* wv) {         // UNCONDITIONAL: no branches,
#pragma unroll                               // no mask dependency
    for (int jj = 0; jj < 4; ++jj)
      wv[jj] = *(const fv*)(wbase + (size_t)(g * 4 + jj) * O);
  };
  auto fma_group = [&](const unsigned* w, const fv* wv) {
#pragma unroll
    for (int jj = 0; jj < 4; ++jj) {
      if (w[jj]) {                           // wave-uniform scalar branch
        const unsigned wj = w[jj];
        GATE_T(0)  GATE_T(1)  GATE_T(2)  GATE_T(3)
        GATE_T(4)  GATE_T(5)  GATE_T(6)  GATE_T(7)
        GATE_T(8)  GATE_T(9)  GATE_T(10) GATE_T(11)
        GATE_T(12) GATE_T(13) GATE_T(14) GATE_T(15)
        GATE_T(16) GATE_T(17) GATE_T(18) GATE_T(19)
        GATE_T(20) GATE_T(21) GATE_T(22) GATE_T(23)
        GATE_T(24) GATE_T(25) GATE_T(26) GATE_T(27)
        GATE_T(28) GATE_T(29) GATE_T(30) GATE_T(31)
      }
    }
  };

  // ping-pong pipeline: A holds group g, B holds g+1; no rotation copies
  unsigned wA[4], wB[4];
  fv wvA[4], wvB[4];
  {
    uint4 mq0 = mload(0);
    uint4 mq1 = mload(G > 1 ? 1 : 0);
    rfl(mq0, wA);
    rfl(mq1, wB);
    wloadU(0, wvA);
  }
  for (int g = 0; g < G; g += 2) {
    const int g2 = (g + 2 < G) ? g + 2 : G - 1;
    const int g3 = (g + 3 < G) ? g + 3 : G - 1;
    uint4 mq2 = mload(g2);                   // depth-2 mask prefetch
    wloadU(g + 1, wvB);                      // unconditional W prefetch
    fma_group(wA, wvA);                      // bodies for g (cond: wA)
    rfl(mq2, wA);                            // wA := masks(g+2)
    uint4 mq3 = mload(g3);
    wloadU(g2, wvA);                         // unconditional W prefetch
    fma_group(wB, wvB);                      // bodies for g+1 (cond: wB)
    rfl(mq3, wB);                            // wB := masks(g+3)
  }

  // ---- epilogue: all in registers (t lives in the lane), no barriers ----
#pragma unroll
  for (int k = 0; k < NAO; ++k) {
    if (FINAL) {
      float v = 0.0f, cur = 0.0f;
#pragma unroll
      for (int t2 = 0; t2 < 32; ++t2) {      // verbatim R3 out_li
        v = v + 0.1f * (cur - v);
        cur = 0.8f * cur + acc[t2][k];
      }
      int o = obase + k;
      if (o < 100) out[(size_t)(bbase + b) * 100 + o] = v;
    } else {
      float v = 0.0f, cur = 0.0f;
      unsigned zw = 0u;
#pragma unroll
      for (int t2 = 0; t2 < 32; ++t2) {      // verbatim R3 lif_int
        v = v + 0.1f * (cur - v);
        unsigned z = ((v - 0.33f) > 0.0f) ? 1u : 0u;
        zw |= z << t2;
        if (z) v = 0.0f;
        cur = 0.8f * cur + acc[t2][k];
      }
      mOut[(size_t)b * O + obase + k] = zw;  // em-format for next layer
    }
  }
}

extern "C" void kernel_launch(void* const* d_in, const int* in_sizes, int n_in,
                              void* d_out, int out_size, void* d_ws, size_t ws_size,
                              hipStream_t stream)
{
  const float* x  = (const float*)d_in[0];
  const float* w1 = (const float*)d_in[1];
  const float* w2 = (const float*)d_in[2];
  const float* w3 = (const float*)d_in[3];
  const float* w4 = (const float*)d_in[4];
  const float* fs = (const float*)d_in[5];
  const float* es = (const float*)d_in[6];
  float* out = (float*)d_out;
  (void)in_sizes; (void)n_in; (void)out_size;

  // ws: WT (5.9 MB) + em + s1m + s2m + s3m (all em-format words)
  int Bc = 2048;
  auto need = [](int bc) -> size_t {
    return ((size_t)WTOT + (size_t)bc * (2048 + 512 + 512 + 256)) * 4;
  };
  while (Bc > 64 && need(Bc) > ws_size) Bc >>= 1;

  float* WT = (float*)d_ws;
  unsigned* em  = (unsigned*)(WT + WTOT);
  unsigned* s1m = em  + (size_t)Bc * 2048;
  unsigned* s2m = s1m + (size_t)Bc * 512;
  unsigned* s3m = s2m + (size_t)Bc * 512;

  prep_kernel<<<(WTOT + THREADS - 1) / THREADS, THREADS, 0, stream>>>(
      w1, w2, w3, w4, WT);

  for (int b0 = 0; b0 < 2048; b0 += Bc) {
    enc_kernel<<<(Bc * 2048) / THREADS, THREADS, 0, stream>>>(x, fs, em, b0);
    // L1: J=2048 -> O=512, scale = 5*encoder_scalar
    gemm_sparse<512, false><<<Bc / 2, THREADS, 0, stream>>>(
        em, WT + WOFF1, 2048, es, s1m, nullptr, 0);
    // L2: J=512 -> O=512
    gemm_sparse<512, false><<<Bc / 2, THREADS, 0, stream>>>(
        s1m, WT + WOFF2, 512, nullptr, s2m, nullptr, 0);
    // L3: J=512 -> O=256
    gemm_sparse<256, false><<<Bc / 4, THREADS, 0, stream>>>(
        s2m, WT + WOFF3, 512, nullptr, s3m, nullptr, 0);
    // L4 (readout): J=256 -> O=128 (padded), LI epilogue -> out
    gemm_sparse<128, true><<<Bc / 4, THREADS, 0, stream>>>(
        s3m, WT + WOFF4, 256, nullptr, nullptr, out, b0);
  }
}